// Round 2
// baseline (474.023 us; speedup 1.0000x reference)
//
#include <hip/hip_runtime.h>
#include <cstdint>
#include <cstddef>

// x[B=512, L=32, H=32, D=128]; per (l,h): Linear(128->128) -> GELU -> Linear(128->128)
#define LH      1024
#define Dd      128
#define BT      64            // batch rows per block (halved for occupancy)
#define MT      4             // 16-row A fragments per block
#define XSTRIDE (LH * Dd)

typedef __attribute__((ext_vector_type(8))) short bf16x8;
typedef __attribute__((ext_vector_type(4))) float f32x4;

// native cast -> compiler emits v_cvt_pk_bf16_f32 (guide m240: don't hand-roll)
static __device__ __forceinline__ short f2bf(float f) {
  return __builtin_bit_cast(short, (__bf16)f);
}

// tanh-form GELU as a single sigmoid: x*sigmoid(1.5957691(x + 0.044715 x^3)).
// max |diff| vs exact-erf gelu ~3e-3, far under the 0.185 threshold; ~8 VALU.
static __device__ __forceinline__ float gelu_fast(float v) {
  float v2 = v * v;
  float u2 = v * (1.5957691216f + 0.0713548163f * v2);
  return v / (1.0f + __expf(-u2));
}

__global__ __launch_bounds__(256, 8) void fused_mlp_kernel(
    const float* __restrict__ x, const float* __restrict__ W1,
    const float* __restrict__ b1, const float* __restrict__ W2,
    const float* __restrict__ b2, float* __restrict__ out) {
  // bf16 H tile [b][e], row stride 256 B, XOR-swizzled (byte ^= (row&7)<<4):
  // b128 reads spread uniformly over all 32 banks (8-way = b128 floor).
  __shared__ alignas(16) short Hs[BT * Dd];   // 16 KB

  const int tid  = threadIdx.x;
  const int lane = tid & 63;
  const int wid  = tid >> 6;     // 4 waves, each owns 32 N-columns
  const int lr   = lane & 15;
  const int lg   = lane >> 4;

  const int bid = blockIdx.x;
  const int lh  = bid & (LH - 1);   // consecutive blocks -> different (l,h); bt sweep reuses W via L3
  const int bt  = bid >> 10;

  const float* w1 = W1 + (size_t)lh * (Dd * Dd);
  const float* w2 = W2 + (size_t)lh * (Dd * Dd);
  const int n0 = wid * 32;

  // bias values for this lane's two output columns (folded into MFMA C-init)
  const float bb1_0 = b1[lh * Dd + n0 + lr];
  const float bb1_1 = b1[lh * Dd + n0 + 16 + lr];
  const float bb2_0 = b2[lh * Dd + n0 + lr];
  const float bb2_1 = b2[lh * Dd + n0 + 16 + lr];

  const float* xa = x + ((size_t)(bt * BT + lr) * LH + lh) * Dd + lg * 8;

  // ---------------- GEMM1: H = gelu(X @ W1 + b1) ----------------
  f32x4 acc[MT][2];
#pragma unroll
  for (int mt = 0; mt < MT; ++mt) {
    acc[mt][0] = (f32x4){bb1_0, bb1_0, bb1_0, bb1_0};
    acc[mt][1] = (f32x4){bb1_1, bb1_1, bb1_1, bb1_1};
  }

#pragma unroll
  for (int ks = 0; ks < 4; ++ks) {
    const int k0 = ks * 32 + lg * 8;
    bf16x8 af[MT];
#pragma unroll
    for (int mt = 0; mt < MT; ++mt) {
      const float4* p = (const float4*)(xa + (size_t)mt * 16 * XSTRIDE + ks * 32);
      float4 u = p[0], v = p[1];
      bf16x8 a;
      a[0] = f2bf(u.x); a[1] = f2bf(u.y); a[2] = f2bf(u.z); a[3] = f2bf(u.w);
      a[4] = f2bf(v.x); a[5] = f2bf(v.y); a[6] = f2bf(v.z); a[7] = f2bf(v.w);
      af[mt] = a;
    }
    bf16x8 bw[2];
#pragma unroll
    for (int nt = 0; nt < 2; ++nt) {
      const float* wp = w1 + (size_t)k0 * Dd + n0 + nt * 16 + lr;
      bf16x8 b;
#pragma unroll
      for (int j = 0; j < 8; ++j) b[j] = f2bf(wp[j * Dd]);
      bw[nt] = b;
    }
#pragma unroll
    for (int mt = 0; mt < MT; ++mt)
#pragma unroll
      for (int nt = 0; nt < 2; ++nt)
        acc[mt][nt] = __builtin_amdgcn_mfma_f32_16x16x32_bf16(af[mt], bw[nt], acc[mt][nt], 0, 0, 0);
  }

  // epilogue 1: GELU -> bf16 -> swizzled LDS
#pragma unroll
  for (int mt = 0; mt < MT; ++mt)
#pragma unroll
    for (int nt = 0; nt < 2; ++nt) {
      const int e = n0 + nt * 16 + lr;
#pragma unroll
      for (int r = 0; r < 4; ++r) {
        const int b = mt * 16 + lg * 4 + r;      // C/D row = (lane>>4)*4 + reg
        float v = gelu_fast(acc[mt][nt][r]);
        const int off = (b * 256 + e * 2) ^ ((b & 7) << 4);
        *(short*)((char*)Hs + off) = f2bf(v);
      }
    }
  __syncthreads();

  // ---------------- GEMM2: out = H @ W2 + b2 ----------------
  f32x4 acc2[MT][2];
#pragma unroll
  for (int mt = 0; mt < MT; ++mt) {
    acc2[mt][0] = (f32x4){bb2_0, bb2_0, bb2_0, bb2_0};
    acc2[mt][1] = (f32x4){bb2_1, bb2_1, bb2_1, bb2_1};
  }

#pragma unroll
  for (int ks = 0; ks < 4; ++ks) {
    const int k0 = ks * 32 + lg * 8;
    bf16x8 af[MT];
#pragma unroll
    for (int mt = 0; mt < MT; ++mt) {
      const int b = mt * 16 + lr;
      const int off = (b * 256 + k0 * 2) ^ ((b & 7) << 4);   // 16B-aligned, uniform banks
      af[mt] = *(const bf16x8*)((const char*)Hs + off);
    }
    bf16x8 bw[2];
#pragma unroll
    for (int nt = 0; nt < 2; ++nt) {
      const float* wp = w2 + (size_t)k0 * Dd + n0 + nt * 16 + lr;
      bf16x8 b;
#pragma unroll
      for (int j = 0; j < 8; ++j) b[j] = f2bf(wp[j * Dd]);
      bw[nt] = b;
    }
#pragma unroll
    for (int mt = 0; mt < MT; ++mt)
#pragma unroll
      for (int nt = 0; nt < 2; ++nt)
        acc2[mt][nt] = __builtin_amdgcn_mfma_f32_16x16x32_bf16(af[mt], bw[nt], acc2[mt][nt], 0, 0, 0);
  }

  // epilogue 2: store f32 (16-lane groups write 64 B contiguous segments)
  {
    float* ob = out + ((size_t)(bt * BT) * LH + lh) * Dd;
#pragma unroll
    for (int mt = 0; mt < MT; ++mt)
#pragma unroll
      for (int nt = 0; nt < 2; ++nt) {
        const int e = n0 + nt * 16 + lr;
#pragma unroll
        for (int r = 0; r < 4; ++r) {
          const int b = mt * 16 + lg * 4 + r;
          ob[(size_t)b * XSTRIDE + e] = acc2[mt][nt][r];
        }
      }
  }
}

extern "C" void kernel_launch(void* const* d_in, const int* in_sizes, int n_in,
                              void* d_out, int out_size, void* d_ws, size_t ws_size,
                              hipStream_t stream) {
  (void)in_sizes; (void)n_in; (void)d_ws; (void)ws_size; (void)out_size;
  const float* x  = (const float*)d_in[0];
  const float* W1 = (const float*)d_in[1];
  const float* b1 = (const float*)d_in[2];
  const float* W2 = (const float*)d_in[3];
  const float* b2 = (const float*)d_in[4];
  float* out = (float*)d_out;
  fused_mlp_kernel<<<dim3(8192), dim3(256), 0, stream>>>(x, W1, b1, W2, b2, out);
}

// Round 3
// 370.507 us; speedup vs baseline: 1.2794x; 1.2794x over previous
//
#include <hip/hip_runtime.h>
#include <cstdint>
#include <cstddef>

// x[B=512, L=32, H=32, D=128]; per (l,h): Linear(128->128) -> GELU -> Linear(128->128)
#define LH      1024
#define Dd      128
#define BT      128           // batch rows per block (round-1 value: perfect HBM traffic)
#define MT      8             // 16-row A fragments per block
#define XSTRIDE (LH * Dd)

typedef __attribute__((ext_vector_type(8))) short bf16x8;
typedef __attribute__((ext_vector_type(4))) float f32x4;

// native cast -> compiler emits v_cvt_pk_bf16_f32 (guide m240)
static __device__ __forceinline__ short f2bf(float f) {
  return __builtin_bit_cast(short, (__bf16)f);
}

// tanh-form GELU as one sigmoid: x*sigmoid(1.5957691(x + 0.044715 x^3)).
// |diff| vs exact-erf gelu ~3e-3 << 0.185 threshold; ~8 VALU vs ~25 for erff.
static __device__ __forceinline__ float gelu_fast(float v) {
  float v2 = v * v;
  float u2 = v * (1.5957691216f + 0.0713548163f * v2);
  return v / (1.0f + __expf(-u2));
}

__global__ __launch_bounds__(256, 4) void fused_mlp_kernel(
    const float* __restrict__ x, const float* __restrict__ W1,
    const float* __restrict__ b1, const float* __restrict__ W2,
    const float* __restrict__ b2, float* __restrict__ out) {
  // bf16 H tile [b][e], row stride 256 B, XOR-swizzled (byte ^= (row&7)<<4).
  __shared__ alignas(16) short Hs[BT * Dd];   // 32 KB -> LDS caps 5 blocks/CU

  const int tid  = threadIdx.x;
  const int lane = tid & 63;
  const int wid  = tid >> 6;     // 4 waves, each owns 32 N-columns
  const int lr   = lane & 15;
  const int lg   = lane >> 4;

  const int bid = blockIdx.x;
  const int lh  = bid & (LH - 1);   // consecutive blocks -> different (l,h); bt sweep reuses W via L3
  const int bt  = bid >> 10;

  const float* w1 = W1 + (size_t)lh * (Dd * Dd);
  const float* w2 = W2 + (size_t)lh * (Dd * Dd);
  const int n0 = wid * 32;

  // bias values for this lane's two output columns (folded into MFMA C-init)
  const float bb1_0 = b1[lh * Dd + n0 + lr];
  const float bb1_1 = b1[lh * Dd + n0 + 16 + lr];
  const float bb2_0 = b2[lh * Dd + n0 + lr];
  const float bb2_1 = b2[lh * Dd + n0 + 16 + lr];

  const float* xa = x + ((size_t)(bt * BT + lr) * LH + lh) * Dd + lg * 8;

  // ---------------- GEMM1: H = gelu(X @ W1 + b1), W2 prefetched alongside ----
  f32x4 acc[MT][2];
#pragma unroll
  for (int mt = 0; mt < MT; ++mt) {
    acc[mt][0] = (f32x4){bb1_0, bb1_0, bb1_0, bb1_0};
    acc[mt][1] = (f32x4){bb1_1, bb1_1, bb1_1, bb1_1};
  }

  bf16x8 bw2[4][2];   // all of this wave's W2 fragments, loaded during GEMM1

#pragma unroll
  for (int ks = 0; ks < 4; ++ks) {
    const int k0 = ks * 32 + lg * 8;
    bf16x8 af[MT];
#pragma unroll
    for (int mt = 0; mt < MT; ++mt) {
      const float4* p = (const float4*)(xa + (size_t)mt * 16 * XSTRIDE + ks * 32);
      float4 u = p[0], v = p[1];
      bf16x8 a;
      a[0] = f2bf(u.x); a[1] = f2bf(u.y); a[2] = f2bf(u.z); a[3] = f2bf(u.w);
      a[4] = f2bf(v.x); a[5] = f2bf(v.y); a[6] = f2bf(v.z); a[7] = f2bf(v.w);
      af[mt] = a;
    }
    bf16x8 bw[2];
#pragma unroll
    for (int nt = 0; nt < 2; ++nt) {
      const float* wp = w1 + (size_t)k0 * Dd + n0 + nt * 16 + lr;
      bf16x8 b;
#pragma unroll
      for (int j = 0; j < 8; ++j) b[j] = f2bf(wp[j * Dd]);
      bw[nt] = b;
    }
    // W2 prefetch: hide its HBM latency under GEMM1's MFMAs so GEMM2 starts
    // immediately after the barrier (kills the post-barrier serial bubble).
#pragma unroll
    for (int nt = 0; nt < 2; ++nt) {
      const float* wp = w2 + (size_t)k0 * Dd + n0 + nt * 16 + lr;
      bf16x8 b;
#pragma unroll
      for (int j = 0; j < 8; ++j) b[j] = f2bf(wp[j * Dd]);
      bw2[ks][nt] = b;
    }
#pragma unroll
    for (int mt = 0; mt < MT; ++mt)
#pragma unroll
      for (int nt = 0; nt < 2; ++nt)
        acc[mt][nt] = __builtin_amdgcn_mfma_f32_16x16x32_bf16(af[mt], bw[nt], acc[mt][nt], 0, 0, 0);
  }

  // epilogue 1: GELU -> bf16 -> swizzled LDS
#pragma unroll
  for (int mt = 0; mt < MT; ++mt)
#pragma unroll
    for (int nt = 0; nt < 2; ++nt) {
      const int e = n0 + nt * 16 + lr;
#pragma unroll
      for (int r = 0; r < 4; ++r) {
        const int b = mt * 16 + lg * 4 + r;      // C/D row = (lane>>4)*4 + reg
        float v = gelu_fast(acc[mt][nt][r]);
        const int off = (b * 256 + e * 2) ^ ((b & 7) << 4);
        *(short*)((char*)Hs + off) = f2bf(v);
      }
    }
  __syncthreads();

  // ---------------- GEMM2: out = H @ W2 + b2 (W2 already in regs) ----------
  f32x4 acc2[MT][2];
#pragma unroll
  for (int mt = 0; mt < MT; ++mt) {
    acc2[mt][0] = (f32x4){bb2_0, bb2_0, bb2_0, bb2_0};
    acc2[mt][1] = (f32x4){bb2_1, bb2_1, bb2_1, bb2_1};
  }

#pragma unroll
  for (int ks = 0; ks < 4; ++ks) {
    const int k0 = ks * 32 + lg * 8;
#pragma unroll
    for (int mt = 0; mt < MT; ++mt) {
      const int b = mt * 16 + lr;
      const int off = (b * 256 + k0 * 2) ^ ((b & 7) << 4);   // 16B-aligned
      bf16x8 a = *(const bf16x8*)((const char*)Hs + off);
#pragma unroll
      for (int nt = 0; nt < 2; ++nt)
        acc2[mt][nt] = __builtin_amdgcn_mfma_f32_16x16x32_bf16(a, bw2[ks][nt], acc2[mt][nt], 0, 0, 0);
    }
  }

  // epilogue 2: bias already folded; nontemporal f32 stores (out never re-read)
  {
    float* ob = out + ((size_t)(bt * BT) * LH + lh) * Dd;
#pragma unroll
    for (int mt = 0; mt < MT; ++mt)
#pragma unroll
      for (int nt = 0; nt < 2; ++nt) {
        const int e = n0 + nt * 16 + lr;
#pragma unroll
        for (int r = 0; r < 4; ++r) {
          const int b = mt * 16 + lg * 4 + r;
          __builtin_nontemporal_store(acc2[mt][nt][r], ob + (size_t)b * XSTRIDE + e);
        }
      }
  }
}

extern "C" void kernel_launch(void* const* d_in, const int* in_sizes, int n_in,
                              void* d_out, int out_size, void* d_ws, size_t ws_size,
                              hipStream_t stream) {
  (void)in_sizes; (void)n_in; (void)d_ws; (void)ws_size; (void)out_size;
  const float* x  = (const float*)d_in[0];
  const float* W1 = (const float*)d_in[1];
  const float* b1 = (const float*)d_in[2];
  const float* W2 = (const float*)d_in[3];
  const float* b2 = (const float*)d_in[4];
  float* out = (float*)d_out;
  fused_mlp_kernel<<<dim3(4096), dim3(256), 0, stream>>>(x, W1, b1, W2, b2, out);
}

// Round 4
// 337.243 us; speedup vs baseline: 1.4056x; 1.0986x over previous
//
#include <hip/hip_runtime.h>
#include <cstdint>
#include <cstddef>

// x[B=512, L=32, H=32, D=128]; per (l,h): Linear(128->128) -> GELU -> Linear(128->128)
#define LH      1024
#define Dd      128
#define BT      128           // batch rows per block (ideal-traffic config from R1)
#define MT      8             // 16-row A fragments per block
#define XSTRIDE (LH * Dd)

typedef __attribute__((ext_vector_type(8))) short bf16x8;
typedef __attribute__((ext_vector_type(4))) float f32x4;

// native cast -> compiler emits v_cvt_pk_bf16_f32 (guide m240)
static __device__ __forceinline__ short f2bf(float f) {
  return __builtin_bit_cast(short, (__bf16)f);
}

// tanh-form GELU as one sigmoid: x*sigmoid(1.5957691(x + 0.044715 x^3)).
// |diff| vs exact-erf gelu ~3e-3 << 0.185 threshold; ~8 VALU vs ~25 for erff.
static __device__ __forceinline__ float gelu_fast(float v) {
  float v2 = v * v;
  float u2 = v * (1.5957691216f + 0.0713548163f * v2);
  return v / (1.0f + __expf(-u2));
}

__global__ __launch_bounds__(256, 4) void fused_mlp_kernel(
    const float* __restrict__ x, const float* __restrict__ W1,
    const float* __restrict__ b1, const float* __restrict__ W2,
    const float* __restrict__ b2, float* __restrict__ out) {
  // bf16 H tile [b][e], row stride 256 B, XOR-swizzled (byte ^= (row&7)<<4).
  __shared__ alignas(16) short Hs[BT * Dd];   // 32 KB -> LDS caps 5 blocks/CU

  const int tid  = threadIdx.x;
  const int lane = tid & 63;
  const int wid  = tid >> 6;     // 4 waves, each owns 32 N-columns
  const int lr   = lane & 15;
  const int lg   = lane >> 4;

  const int bid = blockIdx.x;
  const int lh  = bid & (LH - 1);   // bt=0 sweep (1024 blocks ~ concurrency window) loads W into L3;
  const int bt  = bid >> 10;        // same-lh blocks are 1024 apart -> same XCD (1024%8==0)

  const float* w1 = W1 + (size_t)lh * (Dd * Dd);
  const float* w2 = W2 + (size_t)lh * (Dd * Dd);
  const int n0 = wid * 32;

  // bias values for this lane's two output columns (folded into MFMA C-init)
  const float bb1_0 = b1[lh * Dd + n0 + lr];
  const float bb1_1 = b1[lh * Dd + n0 + 16 + lr];
  const float bb2_0 = b2[lh * Dd + n0 + lr];
  const float bb2_1 = b2[lh * Dd + n0 + 16 + lr];

  const float* xa = x + ((size_t)(bt * BT + lr) * LH + lh) * Dd + lg * 8;

  // ---------------- GEMM1: H = gelu(X @ W1 + b1), W2 prefetched alongside ----
  f32x4 acc[MT][2];
#pragma unroll
  for (int mt = 0; mt < MT; ++mt) {
    acc[mt][0] = (f32x4){bb1_0, bb1_0, bb1_0, bb1_0};
    acc[mt][1] = (f32x4){bb1_1, bb1_1, bb1_1, bb1_1};
  }

  bf16x8 bw2[4][2];   // all of this wave's W2 fragments, loaded during GEMM1

#pragma unroll
  for (int ks = 0; ks < 4; ++ks) {
    const int k0 = ks * 32 + lg * 8;
    bf16x8 af[MT];
#pragma unroll
    for (int mt = 0; mt < MT; ++mt) {
      const float4* p = (const float4*)(xa + (size_t)mt * 16 * XSTRIDE + ks * 32);
      float4 u = p[0], v = p[1];
      bf16x8 a;
      a[0] = f2bf(u.x); a[1] = f2bf(u.y); a[2] = f2bf(u.z); a[3] = f2bf(u.w);
      a[4] = f2bf(v.x); a[5] = f2bf(v.y); a[6] = f2bf(v.z); a[7] = f2bf(v.w);
      af[mt] = a;
    }
    bf16x8 bw[2];
#pragma unroll
    for (int nt = 0; nt < 2; ++nt) {
      const float* wp = w1 + (size_t)k0 * Dd + n0 + nt * 16 + lr;
      bf16x8 b;
#pragma unroll
      for (int j = 0; j < 8; ++j) b[j] = f2bf(wp[j * Dd]);
      bw[nt] = b;
    }
    // W2 prefetch: hide its HBM/L3 latency under GEMM1 so GEMM2 starts
    // immediately after the barrier.
#pragma unroll
    for (int nt = 0; nt < 2; ++nt) {
      const float* wp = w2 + (size_t)k0 * Dd + n0 + nt * 16 + lr;
      bf16x8 b;
#pragma unroll
      for (int j = 0; j < 8; ++j) b[j] = f2bf(wp[j * Dd]);
      bw2[ks][nt] = b;
    }
#pragma unroll
    for (int mt = 0; mt < MT; ++mt)
#pragma unroll
      for (int nt = 0; nt < 2; ++nt)
        acc[mt][nt] = __builtin_amdgcn_mfma_f32_16x16x32_bf16(af[mt], bw[nt], acc[mt][nt], 0, 0, 0);
  }

  // epilogue 1: GELU -> bf16 -> swizzled LDS
#pragma unroll
  for (int mt = 0; mt < MT; ++mt)
#pragma unroll
    for (int nt = 0; nt < 2; ++nt) {
      const int e = n0 + nt * 16 + lr;
#pragma unroll
      for (int r = 0; r < 4; ++r) {
        const int b = mt * 16 + lg * 4 + r;      // C/D row = (lane>>4)*4 + reg
        float v = gelu_fast(acc[mt][nt][r]);
        const int off = (b * 256 + e * 2) ^ ((b & 7) << 4);
        *(short*)((char*)Hs + off) = f2bf(v);
      }
    }
  __syncthreads();

  // ---------------- GEMM2: out = H @ W2 + b2 (W2 already in regs) ----------
  f32x4 acc2[MT][2];
#pragma unroll
  for (int mt = 0; mt < MT; ++mt) {
    acc2[mt][0] = (f32x4){bb2_0, bb2_0, bb2_0, bb2_0};
    acc2[mt][1] = (f32x4){bb2_1, bb2_1, bb2_1, bb2_1};
  }

#pragma unroll
  for (int ks = 0; ks < 4; ++ks) {
    const int k0 = ks * 32 + lg * 8;
#pragma unroll
    for (int mt = 0; mt < MT; ++mt) {
      const int b = mt * 16 + lr;
      const int off = (b * 256 + k0 * 2) ^ ((b & 7) << 4);   // 16B-aligned
      bf16x8 a = *(const bf16x8*)((const char*)Hs + off);
#pragma unroll
      for (int nt = 0; nt < 2; ++nt)
        acc2[mt][nt] = __builtin_amdgcn_mfma_f32_16x16x32_bf16(a, bw2[ks][nt], acc2[mt][nt], 0, 0, 0);
    }
  }

  // epilogue 2: regular f32 stores (R1 showed these hit ideal WRITE_SIZE;
  // nontemporal caused 2.3x write amplification + L3 W eviction in R3)
  {
    float* ob = out + ((size_t)(bt * BT) * LH + lh) * Dd;
#pragma unroll
    for (int mt = 0; mt < MT; ++mt)
#pragma unroll
      for (int nt = 0; nt < 2; ++nt) {
        const int e = n0 + nt * 16 + lr;
#pragma unroll
        for (int r = 0; r < 4; ++r) {
          const int b = mt * 16 + lg * 4 + r;
          ob[(size_t)b * XSTRIDE + e] = acc2[mt][nt][r];
        }
      }
  }
}

extern "C" void kernel_launch(void* const* d_in, const int* in_sizes, int n_in,
                              void* d_out, int out_size, void* d_ws, size_t ws_size,
                              hipStream_t stream) {
  (void)in_sizes; (void)n_in; (void)d_ws; (void)ws_size; (void)out_size;
  const float* x  = (const float*)d_in[0];
  const float* W1 = (const float*)d_in[1];
  const float* b1 = (const float*)d_in[2];
  const float* W2 = (const float*)d_in[3];
  const float* b2 = (const float*)d_in[4];
  float* out = (float*)d_out;
  fused_mlp_kernel<<<dim3(4096), dim3(256), 0, stream>>>(x, W1, b1, W2, b2, out);
}